// Round 1
// baseline (475.055 us; speedup 1.0000x reference)
//
#include <hip/hip_runtime.h>

#define NB 4
#define NN 20000
#define NE 16
#define NC 128
#define M_TOTAL (NB * NN)

#define BM 64
#define BK 32
#define LDA (NC + 4) /* 132: +4 pad keeps 16B alignment, spreads banks */
#define LDW (NC + 4)

// ---------------- inv-sqrt-degree ----------------
__global__ __launch_bounds__(256) void isd_kernel(const int* __restrict__ ei,
                                                  float* __restrict__ isd) {
    int g = blockIdx.x * 256 + threadIdx.x;
    if (g >= M_TOTAL) return;
    const int4* e4 = (const int4*)(ei + (size_t)g * NE);
    int cnt = 1;  // self
#pragma unroll
    for (int q = 0; q < 4; ++q) {
        int4 v = e4[q];
        cnt += (v.x >= 0) + (v.y >= 0) + (v.z >= 0) + (v.w >= 0);
    }
    isd[g] = 1.0f / sqrtf((float)cnt);
}

// ---------------- H = (X @ W^T) * isd ----------------
// X: [M,128] rows, W: [128,128] (h[m][o] = sum_c X[m][c]*W[o][c])
// block: 128 threads (tx 0..15 covers n in 8s, ty 0..7 covers m strided by 8)
__global__ __launch_bounds__(128) void matmul_kernel(const float* __restrict__ X,
                                                     const float* __restrict__ W,
                                                     const float* __restrict__ isd,
                                                     float* __restrict__ H) {
    __shared__ float As[BM][LDA];  // natural [m][k]
    __shared__ float Ws[BK][LDW];  // transposed chunk [k_local][n]
    const int t = threadIdx.x;
    const int tx = t & 15;
    const int ty = t >> 4;
    const int bm = blockIdx.x * BM;

    // stage A (64 rows x 128 cols), float4 coalesced, b128 LDS writes
    {
        const int c = (t & 31) << 2;
        const int m0 = t >> 5;
#pragma unroll
        for (int it = 0; it < 16; ++it) {
            const int m = m0 + (it << 2);
            const float4 v = *(const float4*)(X + (size_t)(bm + m) * NC + c);
            *(float4*)(&As[m][c]) = v;
        }
    }

    float acc[8][8];
#pragma unroll
    for (int i = 0; i < 8; ++i)
#pragma unroll
        for (int j = 0; j < 8; ++j) acc[i][j] = 0.0f;

    for (int kk = 0; kk < NC; kk += BK) {
        __syncthreads();  // protect Ws from previous chunk readers (also covers As store @kk=0)
        {
            // Ws[kl][n] = W[n][kk+kl]
            const int c4 = (t & 7) << 2;
            const int n0 = t >> 3;
#pragma unroll
            for (int it = 0; it < 8; ++it) {
                const int n = n0 + (it << 4);
                const float4 v = *(const float4*)(W + (size_t)n * NC + kk + c4);
                Ws[c4 + 0][n] = v.x;
                Ws[c4 + 1][n] = v.y;
                Ws[c4 + 2][n] = v.z;
                Ws[c4 + 3][n] = v.w;
            }
        }
        __syncthreads();
#pragma unroll 4
        for (int kl = 0; kl < BK; ++kl) {
            float a[8];
#pragma unroll
            for (int i = 0; i < 8; ++i) a[i] = As[ty + (i << 3)][kk + kl];
            const float4 wlo = *(const float4*)(&Ws[kl][tx << 3]);
            const float4 whi = *(const float4*)(&Ws[kl][(tx << 3) + 4]);
            const float w[8] = {wlo.x, wlo.y, wlo.z, wlo.w,
                                whi.x, whi.y, whi.z, whi.w};
#pragma unroll
            for (int i = 0; i < 8; ++i)
#pragma unroll
                for (int j = 0; j < 8; ++j)
                    acc[i][j] = fmaf(a[i], w[j], acc[i][j]);
        }
    }

#pragma unroll
    for (int i = 0; i < 8; ++i) {
        const int m = bm + ty + (i << 3);
        const float sd = isd[m];
        float4 o0, o1;
        o0.x = acc[i][0] * sd; o0.y = acc[i][1] * sd;
        o0.z = acc[i][2] * sd; o0.w = acc[i][3] * sd;
        o1.x = acc[i][4] * sd; o1.y = acc[i][5] * sd;
        o1.z = acc[i][6] * sd; o1.w = acc[i][7] * sd;
        *(float4*)(H + (size_t)m * NC + (tx << 3)) = o0;
        *(float4*)(H + (size_t)m * NC + (tx << 3) + 4) = o1;
    }
}

// ---------------- out = elu((gather_sum(H) + H_self) * isd) ----------------
// one wave per node; lane holds float2 (128 ch / 64 lanes)
__global__ __launch_bounds__(256) void gather_kernel(const float* __restrict__ H,
                                                     const int* __restrict__ ei,
                                                     const float* __restrict__ isd,
                                                     float* __restrict__ out) {
    const int wid = threadIdx.x >> 6;
    const int lane = threadIdx.x & 63;
    int g = blockIdx.x * 4 + wid;
    g = __builtin_amdgcn_readfirstlane(g);
    const int base = (g / NN) * NN;

    const int4* e4 = (const int4*)(ei + (size_t)g * NE);
    const int4 ea = e4[0], eb = e4[1], ec = e4[2], ed = e4[3];
    const int e[NE] = {ea.x, ea.y, ea.z, ea.w, eb.x, eb.y, eb.z, eb.w,
                       ec.x, ec.y, ec.z, ec.w, ed.x, ed.y, ed.z, ed.w};

    const float2* h2 = (const float2*)H;
    float2 acc = h2[(size_t)g * 64 + lane];  // self
#pragma unroll
    for (int q = 0; q < NE; ++q) {
        const int nbr = e[q];
        const int row = base + (nbr & ~(nbr >> 31));  // max(nbr,0)
        const float2 v = h2[(size_t)row * 64 + lane];
        if (nbr >= 0) { acc.x += v.x; acc.y += v.y; }  // uniform branch
    }
    const float sd = isd[g];
    acc.x *= sd; acc.y *= sd;
    acc.x = acc.x > 0.0f ? acc.x : (__expf(acc.x) - 1.0f);
    acc.y = acc.y > 0.0f ? acc.y : (__expf(acc.y) - 1.0f);
    *(float2*)(out + (size_t)g * NC + (lane << 1)) = acc;
}

extern "C" void kernel_launch(void* const* d_in, const int* in_sizes, int n_in,
                              void* d_out, int out_size, void* d_ws, size_t ws_size,
                              hipStream_t stream) {
    const float* x = (const float*)d_in[0];
    const int* ei = (const int*)d_in[1];
    const float* W0 = (const float*)d_in[2];
    const float* W1 = (const float*)d_in[3];
    const float* W2 = (const float*)d_in[4];
    float* out = (float*)d_out;

    float* isd = (float*)d_ws;
    float* h = (float*)((char*)d_ws + (1 << 19));  // +512KB, needs ~41.5MB total ws

    isd_kernel<<<(M_TOTAL + 255) / 256, 256, 0, stream>>>(ei, isd);

    // layer 0: read x -> h -> d_out
    matmul_kernel<<<M_TOTAL / BM, 128, 0, stream>>>(x, W0, isd, h);
    gather_kernel<<<M_TOTAL / 4, 256, 0, stream>>>(h, ei, isd, out);
    // layer 1: read d_out -> h -> d_out
    matmul_kernel<<<M_TOTAL / BM, 128, 0, stream>>>(out, W1, isd, h);
    gather_kernel<<<M_TOTAL / 4, 256, 0, stream>>>(h, ei, isd, out);
    // layer 2
    matmul_kernel<<<M_TOTAL / BM, 128, 0, stream>>>(out, W2, isd, h);
    gather_kernel<<<M_TOTAL / 4, 256, 0, stream>>>(h, ei, isd, out);
}